// Round 9
// baseline (28.430 us; speedup 1.0000x reference)
//
#include <hip/hip_runtime.h>

// B=2, N=512, C_IN=16, C_OUT=16, HID=64
#define NQ   512
#define CI   16
#define CO   16
#define HIDN 64

typedef __attribute__((ext_vector_type(8))) short bf16x8;
typedef __attribute__((ext_vector_type(4))) float f32x4;

// packed bf16 convert: low16 = bf16(a), high16 = bf16(b)
__device__ __forceinline__ unsigned cvt_pk_bf16(float a, float b) {
    unsigned r;
    asm("v_cvt_pk_bf16_f32 %0, %1, %2" : "=v"(r) : "v"(a), "v"(b));
    return r;
}

// ---------------------------------------------------------------------------
// 2048 blocks = 512 (z, even-b pair) x 4 a-quarters. 256 threads = 4 waves;
// each wave owns 32 a x 2 b (same per-lane gelu count as before: 64).
//
// Key change vs round 8: block covers b0 AND b0+1, so each 128B output
// L2 line (= 2 consecutive b x 16 i for one a-row) is written entirely by
// this block, by adjacent store instructions -> full-line writes, no
// partial-line RMW in L2/HBM.
//
// MFMA swapped operands: D^T = M_bf16(hi/lo) . hv^T, i in reg index ->
// contiguous dwordx4 stores. C folded into accumulator init.
// ---------------------------------------------------------------------------
__global__ __launch_bounds__(256, 3) void fused_mfma_kernel(
    const float* __restrict__ features,   // [1024,16]
    const float* __restrict__ geometry,   // [1024,3]
    const float* __restrict__ W1,         // [64,4]
    const float* __restrict__ b1,         // [64]
    const float* __restrict__ W2,         // [256,64]
    const float* __restrict__ b2,         // [256]
    float* __restrict__ out)              // [2,512,512,16]
{
    __shared__ __attribute__((aligned(16))) float M_sm[2][CO][68];
    __shared__ float c_sm[2][CO];
    __shared__ float f_sm[2][CI];

    const int bid = blockIdx.x;
    const int bp  = bid >> 2;            // 0..511 = z*256 + b-pair
    const int aq  = bid & 3;             // a-quarter (128 a each)
    const int z   = bp >> 8;
    const int b0  = (bp & 255) << 1;     // even b
    const int tid = threadIdx.x;

    if (tid < 32) {
        const int bb = tid >> 4, j = tid & 15;
        f_sm[bb][j] = features[(z * NQ + b0 + bb) * CI + j];
    }
    __syncthreads();

    const int wv    = tid >> 6;
    const int lane  = tid & 63;
    const int col   = lane & 15;         // = i for A-frag, = a-offset for B-frag
    const int g     = lane >> 4;
    const int abase = aq * 128 + wv * 32;

    // ---- geometry / rel[t][bb] ----
    float gax[2], gay[2], gaz[2];
    #pragma unroll
    for (int t = 0; t < 2; ++t) {
        const float* ga = geometry + (size_t)(z * NQ + abase + t * 16 + col) * 3;
        gax[t] = ga[0]; gay[t] = ga[1]; gaz[t] = ga[2];
    }
    float rel[2][2][4];
    #pragma unroll
    for (int bb = 0; bb < 2; ++bb) {
        const float gbx = geometry[(z * NQ + b0 + bb) * 3 + 0];
        const float gby = geometry[(z * NQ + b0 + bb) * 3 + 1];
        const float gbz = geometry[(z * NQ + b0 + bb) * 3 + 2];
        #pragma unroll
        for (int t = 0; t < 2; ++t) {
            float rx = gbx - gax[t], ry = gby - gay[t], rz = gbz - gaz[t];
            rel[t][bb][0] = rx; rel[t][bb][1] = ry; rel[t][bb][2] = rz;
            rel[t][bb][3] = sqrtf(fmaf(rx, rx, fmaf(ry, ry, rz * rz)) + 1e-12f);
        }
    }

    // ---- stage A: M for both b's into LDS (W2 tile loaded once) ----
    {
        const int i  = tid >> 4;         // 0..15
        const int k4 = (tid & 15) * 4;   // 0..60
        f32x4 a0v = {0.f, 0.f, 0.f, 0.f};
        f32x4 a1v = {0.f, 0.f, 0.f, 0.f};
        #pragma unroll
        for (int j = 0; j < CI; ++j) {
            const f32x4 w2 = *reinterpret_cast<const f32x4*>(&W2[(i * CI + j) * HIDN + k4]);
            const float f0 = f_sm[0][j], f1 = f_sm[1][j];
            #pragma unroll
            for (int p = 0; p < 4; ++p) {
                a0v[p] = fmaf(f0, w2[p], a0v[p]);
                a1v[p] = fmaf(f1, w2[p], a1v[p]);
            }
        }
        *reinterpret_cast<f32x4*>(&M_sm[0][i][k4]) = a0v;
        *reinterpret_cast<f32x4*>(&M_sm[1][i][k4]) = a1v;
    }
    if (tid < 32) {
        const int bb = tid >> 4, i = tid & 15;
        float acc = 0.f;
        #pragma unroll
        for (int j = 0; j < CI; ++j)
            acc = fmaf(f_sm[bb][j], b2[i * CI + j], acc);
        c_sm[bb][i] = acc;
    }
    __syncthreads();

    // ---- A fragments: hi/lo bf16 split of M (m = i = col), scalar LDS reads ----
    bf16x8 Af[2][2][2];   // [bb][part][kc]
    #pragma unroll
    for (int bb = 0; bb < 2; ++bb) {
        #pragma unroll
        for (int kc = 0; kc < 2; ++kc) {
            const float* mp = &M_sm[bb][col][kc * 32 + g * 8];
            unsigned hpk[4], lpk[4];
            #pragma unroll
            for (int p = 0; p < 4; ++p) {
                float m0 = mp[2 * p], m1 = mp[2 * p + 1];
                unsigned h = cvt_pk_bf16(m0, m1);
                float h0 = __builtin_bit_cast(float, h << 16);
                float h1 = __builtin_bit_cast(float, h & 0xffff0000u);
                hpk[p] = h;
                lpk[p] = cvt_pk_bf16(m0 - h0, m1 - h1);
            }
            union { unsigned u[4]; bf16x8 v; } uh, ul;
            #pragma unroll
            for (int p = 0; p < 4; ++p) { uh.u[p] = hpk[p]; ul.u[p] = lpk[p]; }
            Af[bb][0][kc] = uh.v;
            Af[bb][1][kc] = ul.v;
        }
    }

    // ---- accumulator init: lane (col,g) holds D^T rows i = g*4+r ----
    f32x4 cin[2];
    #pragma unroll
    for (int bb = 0; bb < 2; ++bb)
        #pragma unroll
        for (int r = 0; r < 4; ++r) cin[bb][r] = c_sm[bb][g * 4 + r];
    f32x4 acc[2][2];   // [t][bb]
    #pragma unroll
    for (int t = 0; t < 2; ++t)
        #pragma unroll
        for (int bb = 0; bb < 2; ++bb) acc[t][bb] = cin[bb];

    // ---- main: hv (B-frag: n=a=col, k=g*8+j), 2 MFMAs (hi+lo) per (t,bb,kc) ----
    #pragma unroll
    for (int kc = 0; kc < 2; ++kc) {
        float4 w[8]; float bbias[8];
        #pragma unroll
        for (int j = 0; j < 8; ++j) {
            const int h = kc * 32 + g * 8 + j;
            w[j]     = *reinterpret_cast<const float4*>(W1 + h * 4);
            bbias[j] = b1[h];
        }
        #pragma unroll
        for (int t = 0; t < 2; ++t) {
            #pragma unroll
            for (int bb = 0; bb < 2; ++bb) {
                float hv[8];
                #pragma unroll
                for (int j = 0; j < 8; ++j) {
                    float x = bbias[j];
                    x = fmaf(rel[t][bb][0], w[j].x, x);
                    x = fmaf(rel[t][bb][1], w[j].y, x);
                    x = fmaf(rel[t][bb][2], w[j].z, x);
                    x = fmaf(rel[t][bb][3], w[j].w, x);
                    // gelu (tanh approx, sigmoid form)
                    float q = fmaf(x * x, 0.044715f, 1.0f);
                    float e = __builtin_amdgcn_exp2f((-2.3022082f * x) * q);
                    hv[j]   = x * __builtin_amdgcn_rcpf(1.0f + e);
                }
                union { unsigned u[4]; bf16x8 v; } ua;
                #pragma unroll
                for (int p = 0; p < 4; ++p)
                    ua.u[p] = cvt_pk_bf16(hv[2 * p], hv[2 * p + 1]);
                acc[t][bb] = __builtin_amdgcn_mfma_f32_16x16x32_bf16(Af[bb][0][kc], ua.v, acc[t][bb], 0, 0, 0);
                acc[t][bb] = __builtin_amdgcn_mfma_f32_16x16x32_bf16(Af[bb][1][kc], ua.v, acc[t][bb], 0, 0, 0);
            }
        }
    }

    // ---- epilogue: a-row = abase+t*16+col; b0,b0+1 stores adjacent ->
    //      together they cover the full 128B line of that a-row ----
    #pragma unroll
    for (int t = 0; t < 2; ++t) {
        #pragma unroll
        for (int bb = 0; bb < 2; ++bb) {
            float* op = out + (((size_t)(z * NQ + abase + t * 16 + col)) * NQ + (b0 + bb)) * CO + g * 4;
            *reinterpret_cast<f32x4*>(op) = acc[t][bb];
        }
    }
}

extern "C" void kernel_launch(void* const* d_in, const int* in_sizes, int n_in,
                              void* d_out, int out_size, void* d_ws, size_t ws_size,
                              hipStream_t stream) {
    const float* features = (const float*)d_in[0];
    const float* geometry = (const float*)d_in[1];
    const float* W1       = (const float*)d_in[2];
    const float* b1       = (const float*)d_in[3];
    const float* W2       = (const float*)d_in[4];
    const float* b2       = (const float*)d_in[5];
    float* out = (float*)d_out;

    fused_mfma_kernel<<<2048, 256, 0, stream>>>(
        features, geometry, W1, b1, W2, b2, out);
}

// Round 10
// 25.328 us; speedup vs baseline: 1.1225x; 1.1225x over previous
//
#include <hip/hip_runtime.h>

// B=2, N=512, C_IN=16, C_OUT=16, HID=64
#define NQ   512
#define CI   16
#define CO   16
#define HIDN 64

typedef __attribute__((ext_vector_type(8))) short bf16x8;
typedef __attribute__((ext_vector_type(4))) float f32x4;
typedef __attribute__((ext_vector_type(4))) unsigned u32x4;
typedef __attribute__((ext_vector_type(2))) unsigned u32x2;

// packed bf16 convert: low16 = bf16(a), high16 = bf16(b)
__device__ __forceinline__ unsigned cvt_pk_bf16(float a, float b) {
    unsigned r;
    asm("v_cvt_pk_bf16_f32 %0, %1, %2" : "=v"(r) : "v"(a), "v"(b));
    return r;
}

// ---------------------------------------------------------------------------
// 2048 blocks (2 per zb), 256 threads = 4 waves; each wave owns 64 'a'.
//
// Stage A: M[i][h] = sum_j f[j]*W2[(i*16+j)*64+h] computed in f32, split to
// bf16 hi/lo ONCE, stored in LDS planes with XOR-swizzled 128B rows
// (byte ^= (row&7)<<4; same involution on write and read). Fragment load
// is then a single ds_read_b128 per (part,kc), ~2-way conflicts.
//
// MFMA swapped operands: D^T = M_bf16(hi/lo) . hv^T -> i in reg index ->
// contiguous dwordx4 stores. C-term folded into accumulator init.
// No unions: ext-vector + bit_cast only.
// ---------------------------------------------------------------------------
__global__ __launch_bounds__(256, 4) void fused_mfma_kernel(
    const float* __restrict__ features,   // [1024,16]
    const float* __restrict__ geometry,   // [1024,3]
    const float* __restrict__ W1,         // [64,4]
    const float* __restrict__ b1,         // [64]
    const float* __restrict__ W2,         // [256,64]
    const float* __restrict__ b2,         // [256]
    float* __restrict__ out)              // [2,512,512,16]
{
    __shared__ __attribute__((aligned(16))) unsigned short Mhi[CO * HIDN]; // swizzled [i][k]
    __shared__ __attribute__((aligned(16))) unsigned short Mlo[CO * HIDN];
    __shared__ __attribute__((aligned(16))) float W1_sm[HIDN * 4];
    __shared__ float b1_sm[HIDN];
    __shared__ float c_sm[CO];
    __shared__ float f_sm[CI];

    const int bid = blockIdx.x;
    const int zb  = bid >> 1;            // z*512 + b
    const int a0  = (bid & 1) << 8;
    const int z   = zb >> 9;
    const int b   = zb & 511;
    const int tid = threadIdx.x;

    // ---- coop param staging ----
    W1_sm[tid] = W1[tid];                // 256 floats
    if (tid < HIDN) b1_sm[tid] = b1[tid];
    if (tid < CI)   f_sm[tid]  = features[zb * CI + tid];
    __syncthreads();

    const int wv    = tid >> 6;
    const int lane  = tid & 63;
    const int col   = lane & 15;         // = i for A-frag, = a-offset for B-frag
    const int g     = lane >> 4;
    const int abase = a0 + wv * 64;

    // ---- geometry / rel (independent of stage A; hides latency) ----
    const float gbx = geometry[(z * NQ + b) * 3 + 0];
    const float gby = geometry[(z * NQ + b) * 3 + 1];
    const float gbz = geometry[(z * NQ + b) * 3 + 2];
    float rel[4][4];
    #pragma unroll
    for (int t = 0; t < 4; ++t) {
        const float* ga = geometry + (size_t)(z * NQ + abase + t * 16 + col) * 3;
        float rx = gbx - ga[0], ry = gby - ga[1], rz = gbz - ga[2];
        rel[t][0] = rx; rel[t][1] = ry; rel[t][2] = rz;
        rel[t][3] = sqrtf(fmaf(rx, rx, fmaf(ry, ry, rz * rz)) + 1e-12f);
    }

    // ---- stage A: M (f32) -> bf16 hi/lo planes in LDS, swizzled ----
    {
        const int i  = tid >> 4;         // 0..15
        const int k4 = (tid & 15) << 2;  // 0,4,..,60
        f32x4 m = {0.f, 0.f, 0.f, 0.f};
        #pragma unroll
        for (int j = 0; j < CI; ++j) {
            const f32x4 w2 = *reinterpret_cast<const f32x4*>(&W2[(i * CI + j) * HIDN + k4]);
            const float fj = f_sm[j];
            #pragma unroll
            for (int p = 0; p < 4; ++p) m[p] = fmaf(fj, w2[p], m[p]);
        }
        const unsigned h0 = cvt_pk_bf16(m[0], m[1]);
        const unsigned h1 = cvt_pk_bf16(m[2], m[3]);
        const float f0 = __builtin_bit_cast(float, h0 << 16);
        const float f1 = __builtin_bit_cast(float, h0 & 0xffff0000u);
        const float f2 = __builtin_bit_cast(float, h1 << 16);
        const float f3 = __builtin_bit_cast(float, h1 & 0xffff0000u);
        const unsigned l0 = cvt_pk_bf16(m[0] - f0, m[1] - f1);
        const unsigned l1 = cvt_pk_bf16(m[2] - f2, m[3] - f3);
        const int bir = (k4 << 1) ^ ((i & 7) << 4);   // swizzled byte-in-row
        *reinterpret_cast<u32x2*>(reinterpret_cast<char*>(Mhi) + i * 128 + bir) = (u32x2){h0, h1};
        *reinterpret_cast<u32x2*>(reinterpret_cast<char*>(Mlo) + i * 128 + bir) = (u32x2){l0, l1};
    }
    if (tid < CO) {
        float acc = 0.f;
        #pragma unroll
        for (int j = 0; j < CI; ++j)
            acc = fmaf(f_sm[j], b2[tid * CI + j], acc);
        c_sm[tid] = acc;
    }
    __syncthreads();

    // ---- A fragments: one ds_read_b128 per (part,kc) ----
    bf16x8 Af[2][2];   // [part][kc]
    #pragma unroll
    for (int kc = 0; kc < 2; ++kc) {
        const int bir = (kc * 64 + g * 16) ^ ((col & 7) << 4);
        Af[0][kc] = *reinterpret_cast<const bf16x8*>(reinterpret_cast<const char*>(Mhi) + col * 128 + bir);
        Af[1][kc] = *reinterpret_cast<const bf16x8*>(reinterpret_cast<const char*>(Mlo) + col * 128 + bir);
    }

    // ---- accumulator init: lane (col,g) holds D^T rows i = g*4+r ----
    f32x4 cin;
    #pragma unroll
    for (int r = 0; r < 4; ++r) cin[r] = c_sm[g * 4 + r];
    f32x4 acc[4];
    #pragma unroll
    for (int t = 0; t < 4; ++t) acc[t] = cin;

    // ---- main: hv (B-frag: n=a=col, k=g*8+j), 2 MFMAs (hi+lo) per (t,kc) ----
    #pragma unroll
    for (int kc = 0; kc < 2; ++kc) {
        f32x4 w[8]; float bbias[8];
        #pragma unroll
        for (int j = 0; j < 8; ++j) {
            const int h = kc * 32 + g * 8 + j;
            w[j]     = *reinterpret_cast<const f32x4*>(&W1_sm[h * 4]);  // broadcast LDS
            bbias[j] = b1_sm[h];
        }
        #pragma unroll
        for (int t = 0; t < 4; ++t) {
            float hv[8];
            #pragma unroll
            for (int j = 0; j < 8; ++j) {
                float x = bbias[j];
                x = fmaf(rel[t][0], w[j][0], x);
                x = fmaf(rel[t][1], w[j][1], x);
                x = fmaf(rel[t][2], w[j][2], x);
                x = fmaf(rel[t][3], w[j][3], x);
                // gelu (tanh approx, sigmoid form)
                float q = fmaf(x * x, 0.044715f, 1.0f);
                float e = __builtin_amdgcn_exp2f((-2.3022082f * x) * q);
                hv[j]   = x * __builtin_amdgcn_rcpf(1.0f + e);
            }
            u32x4 up;
            #pragma unroll
            for (int p = 0; p < 4; ++p)
                up[p] = cvt_pk_bf16(hv[2 * p], hv[2 * p + 1]);
            const bf16x8 av = __builtin_bit_cast(bf16x8, up);
            acc[t] = __builtin_amdgcn_mfma_f32_16x16x32_bf16(Af[0][kc], av, acc[t], 0, 0, 0);
            acc[t] = __builtin_amdgcn_mfma_f32_16x16x32_bf16(Af[1][kc], av, acc[t], 0, 0, 0);
        }
    }

    // ---- epilogue: row a = abase+t*16+col, cols i = g*4..g*4+3 -> dwordx4 ----
    #pragma unroll
    for (int t = 0; t < 4; ++t) {
        float* op = out + (((size_t)(z * NQ + abase + t * 16 + col)) * NQ + b) * CO + g * 4;
        *reinterpret_cast<f32x4*>(op) = acc[t];
    }
}

extern "C" void kernel_launch(void* const* d_in, const int* in_sizes, int n_in,
                              void* d_out, int out_size, void* d_ws, size_t ws_size,
                              hipStream_t stream) {
    const float* features = (const float*)d_in[0];
    const float* geometry = (const float*)d_in[1];
    const float* W1       = (const float*)d_in[2];
    const float* b1       = (const float*)d_in[3];
    const float* W2       = (const float*)d_in[4];
    const float* b2       = (const float*)d_in[5];
    float* out = (float*)d_out;

    fused_mfma_kernel<<<2048, 256, 0, stream>>>(
        features, geometry, W1, b1, W2, b2, out);
}